// Round 2
// baseline (602.271 us; speedup 1.0000x reference)
//
#include <hip/hip_runtime.h>

// HyperLSTMCell on MI355X (gfx950).  B=65536, D=128, H=256, Z=128, E=16.
// All inputs/outputs f32; internal GEMMs bf16 MFMA (16x16x32).
//
// Pipeline:
//   cast : abuf[B][512] bf16 = [hhat0 | h0 | x]   (k1 A = cols 0:512, k2 A = cols 128:512)
//   prep : weight images in gate-gathered virtual col order v = hb*256 + gate*64 + hh,
//          pre-swizzled to the LDS image layout; PLUS the zw->dw fold:
//            Wh' = zw_h @ dw_h_blockdiag   (128 x 1024 dense), bh' = zb_h @ dw_h_bd
//            Wx' = zw_x @ dw_x_bd,         bx' = zb_x @ dw_x_bd
//            Wb' = zw_b @ dw_b_bd          (no bias)
//   k1   : gh = abuf @ hweight + hbias ; hyper LSTM -> hhat1,chat1 (f32) + hbuf (bf16 hhat1)
//   k2   : acc1 = [h0|x]@weight (K=384); accH = hbuf@Wh' (K=128); acc1 *= accH+bh';
//          accX = hbuf@Wx'; acc1 *= accX+bx'; accB = hbuf@Wb';
//          g = acc1 + accB + bias ; LSTM -> h1,c1
//
// d_out (f32): h1 [B,256] | c1 [B,256] | hhat1 [B,128] | chat1 [B,128]

typedef unsigned short u16;
typedef __attribute__((ext_vector_type(8))) short bf16x8;   // 8 bf16 (4 VGPRs)
typedef __attribute__((ext_vector_type(4))) float f32x4;

#define BATCH 65536

__device__ __forceinline__ u16 f2b(float f) {           // f32 -> bf16 bits, RNE
  unsigned u = __float_as_uint(f);
  u += 0x7fffu + ((u >> 16) & 1u);
  return (u16)(u >> 16);
}
__device__ __forceinline__ float sigf(float x) { return 1.0f / (1.0f + __expf(-x)); }
// LDS XOR swizzle for [row][64] bf16 tiles (G4: breaks the 128B-row-stride conflict).
__device__ __forceinline__ int swz(int r, int c) { return r * 64 + (c ^ ((r & 7) << 3)); }

// async global->LDS, 16B per lane (m97: global_load_lds_dwordx4)
__device__ __forceinline__ void gl_lds16(const u16* g, u16* l) {
  __builtin_amdgcn_global_load_lds(
      (const __attribute__((address_space(1))) void*)g,
      (__attribute__((address_space(3))) void*)l, 16, 0, 0);
}
// stage 64-row x 64-col A-tile from row-major bf16 (row stride ldk elems) into the
// swizzled LDS image: linear LDS dest + XOR-permuted GLOBAL source chunks (m173).
__device__ __forceinline__ void stageA(const u16* base, int ldk, u16* lA, int t) {
  const int r = t >> 3, q = t & 7, wid = t >> 6;
  const int qs = (q ^ (r & 7)) << 3;                 // (r+32)&7 == r&7
  gl_lds16(base + (size_t)r * ldk + qs, lA + wid * 512);
  gl_lds16(base + (size_t)(r + 32) * ldk + qs, lA + 2048 + wid * 512);
}
// stage 256x64 pre-swizzled B image (linear copy)
__device__ __forceinline__ void stageB(const u16* tile, u16* lB, int t) {
  const int wid = t >> 6;
#pragma unroll
  for (int i = 0; i < 8; ++i)
    gl_lds16(tile + ((size_t)i * 256 + t) * 8, lB + i * 2048 + wid * 512);
}

// ---------------------------------------------------------------------------
// cast: abuf[B][512] = bf16([hhat0 | h0 | x])
// ---------------------------------------------------------------------------
__global__ __launch_bounds__(256) void hlstm_cast(
    const float* __restrict__ hhat0, const float* __restrict__ h0,
    const float* __restrict__ x, u16* __restrict__ abuf)
{
  const size_t stride = (size_t)gridDim.x * blockDim.x;
  for (size_t i = (size_t)blockIdx.x * blockDim.x + threadIdx.x;
       i < (size_t)BATCH * 64; i += stride) {
    const size_t b = i >> 6; const int c = (int)(i & 63);
    const float* src;
    if (c < 16)      src = hhat0 + b * 128 + c * 8;
    else if (c < 48) src = h0 + b * 256 + (size_t)(c - 16) * 8;
    else             src = x + b * 128 + (size_t)(c - 48) * 8;
    float4 v0 = ((const float4*)src)[0];
    float4 v1 = ((const float4*)src)[1];
    alignas(16) u16 o[8] = {f2b(v0.x), f2b(v0.y), f2b(v0.z), f2b(v0.w),
                            f2b(v1.x), f2b(v1.y), f2b(v1.z), f2b(v1.w)};
    *(uint4*)(abuf + i * 8) = *(const uint4*)o;
  }
}

// ---------------------------------------------------------------------------
// prep: weight permute + bf16 cast + pre-swizzle into LDS-image tiles + zw/dw fold
// ---------------------------------------------------------------------------
__global__ void hlstm_prep(
    const float* __restrict__ hweight, const float* __restrict__ hbias,
    const float* __restrict__ zw_h, const float* __restrict__ zw_x, const float* __restrict__ zw_b,
    const float* __restrict__ zb_h, const float* __restrict__ zb_x,
    const float* __restrict__ dw_h, const float* __restrict__ dw_x, const float* __restrict__ dw_b,
    const float* __restrict__ weight, const float* __restrict__ bias,
    u16* __restrict__ hw_ts, float* __restrict__ hbias_r,
    u16* __restrict__ w_ts,  float* __restrict__ bias_r,
    u16* __restrict__ whp_ts, u16* __restrict__ wxp_ts, u16* __restrict__ wbp_ts,
    float* __restrict__ bhp_r, float* __restrict__ bxp_r)
{
  const int tid = blockIdx.x * blockDim.x + threadIdx.x;
  const int nt  = gridDim.x * blockDim.x;

  // hw_ts: [hb(2)][ks(8)] tiles of [n=256][kk=64] at swizzled positions
  for (int i = tid; i < 2 * 8 * 16384; i += nt) {
    int tile = i >> 14, idx = i & 16383;
    int hb = tile >> 3, ks = tile & 7;
    int n = idx >> 6, kk = (idx & 63) ^ ((n & 7) << 3);
    int gate = (n >> 6) & 3, hh = n & 63;
    int k = ks * 64 + kk;
    hw_ts[i] = f2b(hweight[k * 512 + gate * 128 + hb * 64 + hh]);
  }
  // w_ts: [hb(4)][ks(6)] tiles
  for (int i = tid; i < 4 * 6 * 16384; i += nt) {
    int tile = i >> 14, idx = i & 16383;
    int hb = tile / 6, ks = tile % 6;
    int n = idx >> 6, kk = (idx & 63) ^ ((n & 7) << 3);
    int gate = (n >> 6) & 3, hh = n & 63;
    int k = ks * 64 + kk;
    w_ts[i] = f2b(weight[k * 1024 + gate * 256 + hb * 64 + hh]);
  }
  // folded hyper matrices: W'[k][(g,h)] = sum_e zw[k, g*16+e] * dw[g,e,h]
  // images: [mat(3)][hb(4)][ks(2)] tiles of [n=256][kk=64]
  for (int i = tid; i < 3 * 4 * 2 * 16384; i += nt) {
    int mat = i / (8 * 16384), rem = i % (8 * 16384);
    int tile = rem >> 14, idx = rem & 16383;
    int hb = tile >> 1, ks = tile & 1;
    int n = idx >> 6, kk = (idx & 63) ^ ((n & 7) << 3);
    int g = n >> 6, hh = n & 63;
    int k = ks * 64 + kk;                  // 0..127
    int h = hb * 64 + hh;
    const float* zw = (mat == 0) ? zw_h : (mat == 1) ? zw_x : zw_b;
    const float* dw = (mat == 0) ? dw_h : (mat == 1) ? dw_x : dw_b;
    float s = 0.f;
#pragma unroll
    for (int e = 0; e < 16; ++e)
      s += zw[k * 64 + g * 16 + e] * dw[g * 4096 + e * 256 + h];
    u16* dst = (mat == 0) ? whp_ts : (mat == 1) ? wxp_ts : wbp_ts;
    dst[rem] = f2b(s);
  }
  // bias folds (virtual order hb*256 + g*64 + hh)
  for (int i = tid; i < 1024; i += nt) {
    int hb = i >> 8, g = (i >> 6) & 3, hh = i & 63;
    int h = hb * 64 + hh;
    float sh = 0.f, sx = 0.f;
#pragma unroll
    for (int e = 0; e < 16; ++e) {
      sh += zb_h[g * 16 + e] * dw_h[g * 4096 + e * 256 + h];
      sx += zb_x[g * 16 + e] * dw_x[g * 4096 + e * 256 + h];
    }
    bhp_r[i] = sh; bxp_r[i] = sx;
    bias_r[i] = bias[g * 256 + h];
  }
  for (int i = tid; i < 512; i += nt) {
    int gate = (i >> 6) & 3, hb = i >> 8, hh = i & 63;
    hbias_r[i] = hbias[gate * 128 + hb * 64 + hh];
  }
}

// ---------------------------------------------------------------------------
// k1: hyper GEMM (K=512) + hyper LSTM cell. grid (1024, 2), 256 threads.
// ---------------------------------------------------------------------------
__global__ __launch_bounds__(256, 4) void hlstm_k1(
    const u16* __restrict__ abuf, const float* __restrict__ chat0,
    const u16* __restrict__ hw_ts, const float* __restrict__ hbias_r,
    float* __restrict__ d_out, u16* __restrict__ hbuf)
{
  __shared__ alignas(16) u16 lA[64 * 64];
  __shared__ alignas(16) u16 lB[256 * 64];
  const int rb = blockIdx.x, hb = blockIdx.y;
  const int t = threadIdx.x;
  const int lane = t & 63, wc = t >> 6;
  const int lr = lane & 15, kg = lane >> 4;

  f32x4 acc[4][4];
  const f32x4 zzero = {0.f, 0.f, 0.f, 0.f};
#pragma unroll
  for (int mf = 0; mf < 4; ++mf)
#pragma unroll
    for (int g = 0; g < 4; ++g) acc[mf][g] = zzero;

#pragma unroll
  for (int ks = 0; ks < 8; ++ks) {
    __syncthreads();
    stageA(abuf + (size_t)rb * 64 * 512 + ks * 64, 512, lA, t);
    stageB(hw_ts + (size_t)(hb * 8 + ks) * 16384, lB, t);
    __syncthreads();
#pragma unroll
    for (int h = 0; h < 2; ++h) {
      bf16x8 bfr[4];
#pragma unroll
      for (int g = 0; g < 4; ++g)
        bfr[g] = *(const bf16x8*)&lB[swz(g * 64 + wc * 16 + lr, h * 32 + kg * 8)];
#pragma unroll
      for (int mf = 0; mf < 4; ++mf) {
        bf16x8 afr = *(const bf16x8*)&lA[swz(mf * 16 + lr, h * 32 + kg * 8)];
#pragma unroll
        for (int g = 0; g < 4; ++g)
          acc[mf][g] = __builtin_amdgcn_mfma_f32_16x16x32_bf16(afr, bfr[g], acc[mf][g], 0, 0, 0);
      }
    }
  }

  float hb4[4];
#pragma unroll
  for (int g = 0; g < 4; ++g) hb4[g] = hbias_r[hb * 256 + g * 64 + wc * 16 + lr];
  const int zc = hb * 64 + wc * 16 + lr;
  float* out_hh = d_out + (size_t)BATCH * 512;
  float* out_ch = d_out + (size_t)BATCH * 640;
#pragma unroll
  for (int mf = 0; mf < 4; ++mf)
#pragma unroll
    for (int r = 0; r < 4; ++r) {
      const int row = rb * 64 + mf * 16 + kg * 4 + r;
      const float gi = acc[mf][0][r] + hb4[0];
      const float gg = acc[mf][1][r] + hb4[1];
      const float gf = acc[mf][2][r] + hb4[2];
      const float go = acc[mf][3][r] + hb4[3];
      const float c0v = chat0[(size_t)row * 128 + zc];
      const float c1v = sigf(gf) * c0v + sigf(gi) * tanhf(gg);
      const float h1v = sigf(go) * tanhf(c1v);
      out_hh[(size_t)row * 128 + zc] = h1v;
      out_ch[(size_t)row * 128 + zc] = c1v;
      hbuf[(size_t)row * 128 + zc] = f2b(h1v);
    }
}

// ---------------------------------------------------------------------------
// k2: main GEMM (K=384) + 3 dense folded hyper-GEMMs (K=128) + LSTM epilogue.
// grid (1024, 4), 256 threads.
// ---------------------------------------------------------------------------
__global__ __launch_bounds__(256, 3) void hlstm_k2(
    const u16* __restrict__ abuf, const u16* __restrict__ hbuf,
    const float* __restrict__ c0,
    const u16* __restrict__ w_ts, const float* __restrict__ bias_r,
    const u16* __restrict__ whp_ts, const u16* __restrict__ wxp_ts, const u16* __restrict__ wbp_ts,
    const float* __restrict__ bhp_r, const float* __restrict__ bxp_r,
    float* __restrict__ d_out)
{
  __shared__ alignas(16) u16 lA[64 * 64];
  __shared__ alignas(16) u16 lB[256 * 64];
  const int rb = blockIdx.x, hb = blockIdx.y;
  const int t = threadIdx.x;
  const int lane = t & 63, wc = t >> 6;
  const int lr = lane & 15, kg = lane >> 4;

  f32x4 acc1[4][4], acc2[4][4];
  const f32x4 zzero = {0.f, 0.f, 0.f, 0.f};

  auto sweep = [&](f32x4 (&acc)[4][4]) {
#pragma unroll
    for (int h = 0; h < 2; ++h) {
      bf16x8 bfr[4];
#pragma unroll
      for (int g = 0; g < 4; ++g)
        bfr[g] = *(const bf16x8*)&lB[swz(g * 64 + wc * 16 + lr, h * 32 + kg * 8)];
#pragma unroll
      for (int mf = 0; mf < 4; ++mf) {
        bf16x8 afr = *(const bf16x8*)&lA[swz(mf * 16 + lr, h * 32 + kg * 8)];
#pragma unroll
        for (int g = 0; g < 4; ++g)
          acc[mf][g] = __builtin_amdgcn_mfma_f32_16x16x32_bf16(afr, bfr[g], acc[mf][g], 0, 0, 0);
      }
    }
  };

  const float* bias4 = bias_r + hb * 256;
  float b4[4], bh4[4], bx4[4];
#pragma unroll
  for (int g = 0; g < 4; ++g) {
    b4[g]  = bias4[g * 64 + wc * 16 + lr];
    bh4[g] = bhp_r[hb * 256 + g * 64 + wc * 16 + lr];
    bx4[g] = bxp_r[hb * 256 + g * 64 + wc * 16 + lr];
  }

  // ---- main: acc1 = [h0|x] @ weight  (abuf cols 128..512, K=384)
#pragma unroll
  for (int mf = 0; mf < 4; ++mf)
#pragma unroll
    for (int g = 0; g < 4; ++g) acc1[mf][g] = zzero;
#pragma unroll
  for (int ks = 0; ks < 6; ++ks) {
    __syncthreads();
    stageA(abuf + (size_t)rb * 64 * 512 + 128 + ks * 64, 512, lA, t);
    stageB(w_ts + (size_t)(hb * 6 + ks) * 16384, lB, t);
    __syncthreads();
    sweep(acc1);
  }

  // ---- three folded hyper phases (A = hbuf, K=128 each), merged in-register
#pragma unroll
  for (int ph = 0; ph < 3; ++ph) {
    const u16* wp = (ph == 0) ? whp_ts : (ph == 1) ? wxp_ts : wbp_ts;
#pragma unroll
    for (int mf = 0; mf < 4; ++mf)
#pragma unroll
      for (int g = 0; g < 4; ++g) acc2[mf][g] = zzero;
#pragma unroll
    for (int ks = 0; ks < 2; ++ks) {
      __syncthreads();
      stageA(hbuf + (size_t)rb * 64 * 128 + ks * 64, 128, lA, t);
      stageB(wp + (size_t)(hb * 2 + ks) * 16384, lB, t);
      __syncthreads();
      sweep(acc2);
    }
    if (ph == 0) {      // acc1 *= d_yh
#pragma unroll
      for (int mf = 0; mf < 4; ++mf)
#pragma unroll
        for (int g = 0; g < 4; ++g)
#pragma unroll
          for (int r = 0; r < 4; ++r) acc1[mf][g][r] *= (acc2[mf][g][r] + bh4[g]);
    } else if (ph == 1) { // acc1 *= d_yx
#pragma unroll
      for (int mf = 0; mf < 4; ++mf)
#pragma unroll
        for (int g = 0; g < 4; ++g)
#pragma unroll
          for (int r = 0; r < 4; ++r) acc1[mf][g][r] *= (acc2[mf][g][r] + bx4[g]);
    }
    // ph == 2: acc2 = d_yb, added in epilogue
  }

  // ---- epilogue: main LSTM cell
  const int hcol = hb * 64 + wc * 16 + lr;
  float* out_c1 = d_out + (size_t)BATCH * 256;
#pragma unroll
  for (int mf = 0; mf < 4; ++mf)
#pragma unroll
    for (int r = 0; r < 4; ++r) {
      const int row = rb * 64 + mf * 16 + kg * 4 + r;
      const float gi = acc1[mf][0][r] + acc2[mf][0][r] + b4[0];
      const float gg = acc1[mf][1][r] + acc2[mf][1][r] + b4[1];
      const float gf = acc1[mf][2][r] + acc2[mf][2][r] + b4[2];
      const float go = acc1[mf][3][r] + acc2[mf][3][r] + b4[3];
      const float c0v = c0[(size_t)row * 256 + hcol];
      const float c1v = sigf(gf) * c0v + sigf(gi) * tanhf(gg);
      const float h1v = sigf(go) * tanhf(c1v);
      d_out[(size_t)row * 256 + hcol]  = h1v;
      out_c1[(size_t)row * 256 + hcol] = c1v;
    }
}

// ---------------------------------------------------------------------------
extern "C" void kernel_launch(void* const* d_in, const int* in_sizes, int n_in,
                              void* d_out, int out_size, void* d_ws, size_t ws_size,
                              hipStream_t stream)
{
  (void)in_sizes; (void)n_in; (void)out_size; (void)ws_size;
  const float* x       = (const float*)d_in[0];
  const float* h0      = (const float*)d_in[1];
  const float* c0      = (const float*)d_in[2];
  const float* hhat0   = (const float*)d_in[3];
  const float* chat0   = (const float*)d_in[4];
  const float* hweight = (const float*)d_in[5];
  const float* hbias   = (const float*)d_in[6];
  const float* zw_h    = (const float*)d_in[7];
  const float* zw_x    = (const float*)d_in[8];
  const float* zw_b    = (const float*)d_in[9];
  const float* zb_h    = (const float*)d_in[10];
  const float* zb_x    = (const float*)d_in[11];
  const float* dw_h    = (const float*)d_in[12];
  const float* dw_x    = (const float*)d_in[13];
  const float* dw_b    = (const float*)d_in[14];
  const float* weight  = (const float*)d_in[15];
  const float* bias    = (const float*)d_in[16];

  // workspace layout (bytes, 16B-aligned); total ~86 MB
  char* wsb = (char*)d_ws;
  u16*   abuf    = (u16*)(wsb + 0);              // B*512*2   = 67108864
  u16*   hbuf    = (u16*)(wsb + 67108864);       // B*128*2   = 16777216
  u16*   hw_ts   = (u16*)(wsb + 83886080);       // 2*8*16384*2 = 524288
  u16*   w_ts    = (u16*)(wsb + 84410368);       // 4*6*16384*2 = 786432
  u16*   whp_ts  = (u16*)(wsb + 85196800);       // 4*2*16384*2 = 262144
  u16*   wxp_ts  = (u16*)(wsb + 85458944);
  u16*   wbp_ts  = (u16*)(wsb + 85721088);
  float* hbias_r = (float*)(wsb + 85983232);     // 512*4
  float* bias_r  = (float*)(wsb + 85985280);     // 1024*4
  float* bhp_r   = (float*)(wsb + 85989376);     // 1024*4
  float* bxp_r   = (float*)(wsb + 85993472);     // 1024*4

  hlstm_cast<<<dim3(4096), dim3(256), 0, stream>>>(hhat0, h0, x, abuf);

  hlstm_prep<<<dim3(512), dim3(256), 0, stream>>>(
      hweight, hbias, zw_h, zw_x, zw_b, zb_h, zb_x, dw_h, dw_x, dw_b, weight, bias,
      hw_ts, hbias_r, w_ts, bias_r, whp_ts, wxp_ts, wbp_ts, bhp_r, bxp_r);

  hlstm_k1<<<dim3(1024, 2), dim3(256), 0, stream>>>(
      abuf, chat0, hw_ts, hbias_r, (float*)d_out, hbuf);

  hlstm_k2<<<dim3(1024, 4), dim3(256), 0, stream>>>(
      abuf, hbuf, c0, w_ts, bias_r, whp_ts, wxp_ts, wbp_ts, bhp_r, bxp_r, (float*)d_out);
}

// Round 3
// 490.397 us; speedup vs baseline: 1.2281x; 1.2281x over previous
//
#include <hip/hip_runtime.h>

// HyperLSTMCell on MI355X (gfx950).  B=65536, D=128, H=256, Z=128, E=16.
// All inputs/outputs f32; internal GEMMs bf16 MFMA (16x16x32).
//
// Pipeline:
//   pre  : [fused] cast abuf[B][512] bf16 = [hhat0|h0|x]  +  weight prep:
//          gate-gathered virtual col order v = hb*256 + gate*64 + hh, pre-swizzled
//          LDS images; zw->dw fold: Wh' = zw_h@dw_h_bd (128x1024 dense), bh' = zb_h@dw_h_bd,
//          same for x; Wb' = zw_b@dw_b_bd.
//   k1   : gh = abuf@hweight + hbias ; hyper LSTM -> hhat1,chat1 (f32) + hbuf (bf16)
//          [2-phase double-buffered LDS pipeline, global_load_lds staging]
//   k2   : acc1 = [h0|x]@weight (K=384); accH = hbuf@Wh'; acc1 *= accH+bh';
//          accX = hbuf@Wx'; acc1 *= accX+bx'; accB = hbuf@Wb';
//          g = acc1 + accB + bias ; LSTM -> h1,c1   [12 flat K-steps, same pipeline]
//
// d_out (f32): h1 [B,256] | c1 [B,256] | hhat1 [B,128] | chat1 [B,128]

typedef unsigned short u16;
typedef __attribute__((ext_vector_type(8))) short bf16x8;   // 8 bf16 (4 VGPRs)
typedef __attribute__((ext_vector_type(4))) float f32x4;

#define BATCH 65536

__device__ __forceinline__ u16 f2b(float f) {           // f32 -> bf16 bits, RNE
  unsigned u = __float_as_uint(f);
  u += 0x7fffu + ((u >> 16) & 1u);
  return (u16)(u >> 16);
}
__device__ __forceinline__ float sigf(float x) { return 1.0f / (1.0f + __expf(-x)); }
// LDS XOR swizzle for [row][64] bf16 tiles (G4: breaks the 128B-row-stride conflict).
__device__ __forceinline__ int swz(int r, int c) { return r * 64 + (c ^ ((r & 7) << 3)); }

// async global->LDS, 16B per lane (m97: global_load_lds_dwordx4)
__device__ __forceinline__ void gl_lds16(const u16* g, u16* l) {
  __builtin_amdgcn_global_load_lds(
      (const __attribute__((address_space(1))) void*)g,
      (__attribute__((address_space(3))) void*)l, 16, 0, 0);
}
// stage 64-row x 64-col A-tile from row-major bf16 (row stride ldk elems) into the
// swizzled LDS image: linear LDS dest + XOR-permuted GLOBAL source chunks (m173).
__device__ __forceinline__ void stageA(const u16* base, int ldk, u16* lA, int t) {
  const int r = t >> 3, q = t & 7, wid = t >> 6;
  const int qs = (q ^ (r & 7)) << 3;                 // (r+32)&7 == r&7
  gl_lds16(base + (size_t)r * ldk + qs, lA + wid * 512);
  gl_lds16(base + (size_t)(r + 32) * ldk + qs, lA + 2048 + wid * 512);
}
// stage 256x64 pre-swizzled B image (linear copy)
__device__ __forceinline__ void stageB(const u16* tile, u16* lB, int t) {
  const int wid = t >> 6;
#pragma unroll
  for (int i = 0; i < 8; ++i)
    gl_lds16(tile + ((size_t)i * 256 + t) * 8, lB + i * 2048 + wid * 512);
}

// ---------------------------------------------------------------------------
// pre: fused input-cast + weight prep.
//   blocks [0, 4096)   : abuf[B][512] = bf16([hhat0 | h0 | x])
//   blocks [4096, 4608): weight permute/cast/swizzle + zw->dw fold
// ---------------------------------------------------------------------------
__global__ __launch_bounds__(256) void hlstm_pre(
    const float* __restrict__ hhat0, const float* __restrict__ h0,
    const float* __restrict__ x, u16* __restrict__ abuf,
    const float* __restrict__ hweight, const float* __restrict__ hbias,
    const float* __restrict__ zw_h, const float* __restrict__ zw_x, const float* __restrict__ zw_b,
    const float* __restrict__ zb_h, const float* __restrict__ zb_x,
    const float* __restrict__ dw_h, const float* __restrict__ dw_x, const float* __restrict__ dw_b,
    const float* __restrict__ weight, const float* __restrict__ bias,
    u16* __restrict__ hw_ts, float* __restrict__ hbias_r,
    u16* __restrict__ w_ts,  float* __restrict__ bias_r,
    u16* __restrict__ whp_ts, u16* __restrict__ wxp_ts, u16* __restrict__ wbp_ts,
    float* __restrict__ bhp_r, float* __restrict__ bxp_r)
{
  if (blockIdx.x < 4096) {
    // ---- cast part
    const size_t stride = (size_t)4096 * 256;
    for (size_t i = (size_t)blockIdx.x * 256 + threadIdx.x;
         i < (size_t)BATCH * 64; i += stride) {
      const size_t b = i >> 6; const int c = (int)(i & 63);
      const float* src;
      if (c < 16)      src = hhat0 + b * 128 + c * 8;
      else if (c < 48) src = h0 + b * 256 + (size_t)(c - 16) * 8;
      else             src = x + b * 128 + (size_t)(c - 48) * 8;
      float4 v0 = ((const float4*)src)[0];
      float4 v1 = ((const float4*)src)[1];
      alignas(16) u16 o[8] = {f2b(v0.x), f2b(v0.y), f2b(v0.z), f2b(v0.w),
                              f2b(v1.x), f2b(v1.y), f2b(v1.z), f2b(v1.w)};
      *(uint4*)(abuf + i * 8) = *(const uint4*)o;
    }
    return;
  }
  // ---- prep part
  const int tid = (blockIdx.x - 4096) * 256 + threadIdx.x;
  const int nt  = 512 * 256;

  // hw_ts: [hb(2)][ks(8)] tiles of [n=256][kk=64] at swizzled positions
  for (int i = tid; i < 2 * 8 * 16384; i += nt) {
    int tile = i >> 14, idx = i & 16383;
    int hb = tile >> 3, ks = tile & 7;
    int n = idx >> 6, kk = (idx & 63) ^ ((n & 7) << 3);
    int gate = (n >> 6) & 3, hh = n & 63;
    int k = ks * 64 + kk;
    hw_ts[i] = f2b(hweight[k * 512 + gate * 128 + hb * 64 + hh]);
  }
  // w_ts: [hb(4)][ks(6)] tiles
  for (int i = tid; i < 4 * 6 * 16384; i += nt) {
    int tile = i >> 14, idx = i & 16383;
    int hb = tile / 6, ks = tile % 6;
    int n = idx >> 6, kk = (idx & 63) ^ ((n & 7) << 3);
    int gate = (n >> 6) & 3, hh = n & 63;
    int k = ks * 64 + kk;
    w_ts[i] = f2b(weight[k * 1024 + gate * 256 + hb * 64 + hh]);
  }
  // folded hyper matrices: W'[k][(g,h)] = sum_e zw[k, g*16+e] * dw[g,e,h]
  // images: [mat(3)][hb(4)][ks(2)] tiles of [n=256][kk=64]
  for (int i = tid; i < 3 * 4 * 2 * 16384; i += nt) {
    int mat = i / (8 * 16384), rem = i % (8 * 16384);
    int tile = rem >> 14, idx = rem & 16383;
    int hb = tile >> 1, ks = tile & 1;
    int n = idx >> 6, kk = (idx & 63) ^ ((n & 7) << 3);
    int g = n >> 6, hh = n & 63;
    int k = ks * 64 + kk;                  // 0..127
    int h = hb * 64 + hh;
    const float* zw = (mat == 0) ? zw_h : (mat == 1) ? zw_x : zw_b;
    const float* dw = (mat == 0) ? dw_h : (mat == 1) ? dw_x : dw_b;
    float s = 0.f;
#pragma unroll
    for (int e = 0; e < 16; ++e)
      s += zw[k * 64 + g * 16 + e] * dw[g * 4096 + e * 256 + h];
    u16* dst = (mat == 0) ? whp_ts : (mat == 1) ? wxp_ts : wbp_ts;
    dst[rem] = f2b(s);
  }
  // bias folds (virtual order hb*256 + g*64 + hh)
  for (int i = tid; i < 1024; i += nt) {
    int hb = i >> 8, g = (i >> 6) & 3, hh = i & 63;
    int h = hb * 64 + hh;
    float sh = 0.f, sx = 0.f;
#pragma unroll
    for (int e = 0; e < 16; ++e) {
      sh += zb_h[g * 16 + e] * dw_h[g * 4096 + e * 256 + h];
      sx += zb_x[g * 16 + e] * dw_x[g * 4096 + e * 256 + h];
    }
    bhp_r[i] = sh; bxp_r[i] = sx;
    bias_r[i] = bias[g * 256 + h];
  }
  for (int i = tid; i < 512; i += nt) {
    int gate = (i >> 6) & 3, hb = i >> 8, hh = i & 63;
    hbias_r[i] = hbias[gate * 128 + hb * 64 + hh];
  }
}

// ---------------------------------------------------------------------------
// k1: hyper GEMM (K=512) + hyper LSTM. grid (1024, 2), 256 threads.
// 2-phase double-buffered: stage(next) -> compute(cur) -> barrier.
// ---------------------------------------------------------------------------
__global__ __launch_bounds__(256) void hlstm_k1(
    const u16* __restrict__ abuf, const float* __restrict__ chat0,
    const u16* __restrict__ hw_ts, const float* __restrict__ hbias_r,
    float* __restrict__ d_out, u16* __restrict__ hbuf)
{
  __shared__ alignas(16) u16 lA[2][64 * 64];
  __shared__ alignas(16) u16 lB[2][256 * 64];
  const int rb = blockIdx.x, hb = blockIdx.y;
  const int t = threadIdx.x;
  const int lane = t & 63, wc = t >> 6;
  const int lr = lane & 15, kg = lane >> 4;

  f32x4 acc[4][4];
  const f32x4 zzero = {0.f, 0.f, 0.f, 0.f};
#pragma unroll
  for (int mf = 0; mf < 4; ++mf)
#pragma unroll
    for (int g = 0; g < 4; ++g) acc[mf][g] = zzero;

  const u16* arow = abuf + (size_t)rb * 64 * 512;

  stageA(arow, 512, lA[0], t);
  stageB(hw_ts + (size_t)(hb * 8) * 16384, lB[0], t);
  __syncthreads();

#pragma unroll
  for (int ks = 0; ks < 8; ++ks) {
    const int cur = ks & 1, nxt = cur ^ 1;
    if (ks < 7) {
      stageA(arow + (ks + 1) * 64, 512, lA[nxt], t);
      stageB(hw_ts + (size_t)(hb * 8 + ks + 1) * 16384, lB[nxt], t);
    }
#pragma unroll
    for (int h = 0; h < 2; ++h) {
      bf16x8 bfr[4];
#pragma unroll
      for (int g = 0; g < 4; ++g)
        bfr[g] = *(const bf16x8*)&lB[cur][swz(g * 64 + wc * 16 + lr, h * 32 + kg * 8)];
#pragma unroll
      for (int mf = 0; mf < 4; ++mf) {
        bf16x8 afr = *(const bf16x8*)&lA[cur][swz(mf * 16 + lr, h * 32 + kg * 8)];
#pragma unroll
        for (int g = 0; g < 4; ++g)
          acc[mf][g] = __builtin_amdgcn_mfma_f32_16x16x32_bf16(afr, bfr[g], acc[mf][g], 0, 0, 0);
      }
    }
    __syncthreads();
  }

  float hb4[4];
#pragma unroll
  for (int g = 0; g < 4; ++g) hb4[g] = hbias_r[hb * 256 + g * 64 + wc * 16 + lr];
  const int zc = hb * 64 + wc * 16 + lr;
  float* out_hh = d_out + (size_t)BATCH * 512;
  float* out_ch = d_out + (size_t)BATCH * 640;
#pragma unroll
  for (int mf = 0; mf < 4; ++mf)
#pragma unroll
    for (int r = 0; r < 4; ++r) {
      const int row = rb * 64 + mf * 16 + kg * 4 + r;
      const float gi = acc[mf][0][r] + hb4[0];
      const float gg = acc[mf][1][r] + hb4[1];
      const float gf = acc[mf][2][r] + hb4[2];
      const float go = acc[mf][3][r] + hb4[3];
      const float c0v = chat0[(size_t)row * 128 + zc];
      const float c1v = sigf(gf) * c0v + sigf(gi) * tanhf(gg);
      const float h1v = sigf(go) * tanhf(c1v);
      out_hh[(size_t)row * 128 + zc] = h1v;
      out_ch[(size_t)row * 128 + zc] = c1v;
      hbuf[(size_t)row * 128 + zc] = f2b(h1v);
    }
}

// ---------------------------------------------------------------------------
// k2: 12 flat K-steps — 6 x main GEMM (K=384) then 3 x 2 folded hyper (K=128
// each) — in one 2-phase double-buffered pipeline. grid (1024, 4), 256 thr.
// ---------------------------------------------------------------------------
__global__ __launch_bounds__(256) void hlstm_k2(
    const u16* __restrict__ abuf, const u16* __restrict__ hbuf,
    const float* __restrict__ c0,
    const u16* __restrict__ w_ts, const float* __restrict__ bias_r,
    const u16* __restrict__ whp_ts, const u16* __restrict__ wxp_ts, const u16* __restrict__ wbp_ts,
    const float* __restrict__ bhp_r, const float* __restrict__ bxp_r,
    float* __restrict__ d_out)
{
  __shared__ alignas(16) u16 lA[2][64 * 64];
  __shared__ alignas(16) u16 lB[2][256 * 64];
  const int rb = blockIdx.x, hb = blockIdx.y;
  const int t = threadIdx.x;
  const int lane = t & 63, wc = t >> 6;
  const int lr = lane & 15, kg = lane >> 4;

  const u16* amain = abuf + (size_t)rb * 64 * 512 + 128;   // [h0|x] cols, ld 512
  const u16* ahyp  = hbuf + (size_t)rb * 64 * 128;         // ld 128

  // per-step sources (s = 0..11)
  auto aptr = [&](int s) -> const u16* {
    return (s < 6) ? (amain + s * 64) : (ahyp + ((s - 6) & 1) * 64);
  };
  auto aldk = [&](int s) -> int { return (s < 6) ? 512 : 128; };
  auto bptr = [&](int s) -> const u16* {
    if (s < 6) return w_ts + (size_t)(hb * 6 + s) * 16384;
    const int ph = (s - 6) >> 1, ks = (s - 6) & 1;
    const u16* wp = (ph == 0) ? whp_ts : (ph == 1) ? wxp_ts : wbp_ts;
    return wp + (size_t)(hb * 2 + ks) * 16384;
  };

  f32x4 acc1[4][4], acc2[4][4];
  const f32x4 zzero = {0.f, 0.f, 0.f, 0.f};
#pragma unroll
  for (int mf = 0; mf < 4; ++mf)
#pragma unroll
    for (int g = 0; g < 4; ++g) acc1[mf][g] = zzero;

  float b4[4], bh4[4], bx4[4];
#pragma unroll
  for (int g = 0; g < 4; ++g) {
    b4[g]  = bias_r[hb * 256 + g * 64 + wc * 16 + lr];
    bh4[g] = bhp_r[hb * 256 + g * 64 + wc * 16 + lr];
    bx4[g] = bxp_r[hb * 256 + g * 64 + wc * 16 + lr];
  }

  stageA(aptr(0), aldk(0), lA[0], t);
  stageB(bptr(0), lB[0], t);
  __syncthreads();

#pragma unroll
  for (int s = 0; s < 12; ++s) {
    const int cur = s & 1, nxt = cur ^ 1;
    if (s < 11) {
      stageA(aptr(s + 1), aldk(s + 1), lA[nxt], t);
      stageB(bptr(s + 1), lB[nxt], t);
    }
    if (s == 6 || s == 8 || s == 10) {
#pragma unroll
      for (int mf = 0; mf < 4; ++mf)
#pragma unroll
        for (int g = 0; g < 4; ++g) acc2[mf][g] = zzero;
    }
    // compute step s into acc1 (s<6) or acc2 (s>=6)
#pragma unroll
    for (int h = 0; h < 2; ++h) {
      bf16x8 bfr[4];
#pragma unroll
      for (int g = 0; g < 4; ++g)
        bfr[g] = *(const bf16x8*)&lB[cur][swz(g * 64 + wc * 16 + lr, h * 32 + kg * 8)];
#pragma unroll
      for (int mf = 0; mf < 4; ++mf) {
        bf16x8 afr = *(const bf16x8*)&lA[cur][swz(mf * 16 + lr, h * 32 + kg * 8)];
#pragma unroll
        for (int g = 0; g < 4; ++g) {
          if (s < 6)
            acc1[mf][g] = __builtin_amdgcn_mfma_f32_16x16x32_bf16(afr, bfr[g], acc1[mf][g], 0, 0, 0);
          else
            acc2[mf][g] = __builtin_amdgcn_mfma_f32_16x16x32_bf16(afr, bfr[g], acc2[mf][g], 0, 0, 0);
        }
      }
    }
    if (s == 7) {        // acc1 *= d_yh
#pragma unroll
      for (int mf = 0; mf < 4; ++mf)
#pragma unroll
        for (int g = 0; g < 4; ++g)
#pragma unroll
          for (int r = 0; r < 4; ++r) acc1[mf][g][r] *= (acc2[mf][g][r] + bh4[g]);
    } else if (s == 9) { // acc1 *= d_yx
#pragma unroll
      for (int mf = 0; mf < 4; ++mf)
#pragma unroll
        for (int g = 0; g < 4; ++g)
#pragma unroll
          for (int r = 0; r < 4; ++r) acc1[mf][g][r] *= (acc2[mf][g][r] + bx4[g]);
    }
    __syncthreads();
  }

  // ---- epilogue: main LSTM cell (acc2 holds d_yb)
  const int hcol = hb * 64 + wc * 16 + lr;
  float* out_c1 = d_out + (size_t)BATCH * 256;
#pragma unroll
  for (int mf = 0; mf < 4; ++mf)
#pragma unroll
    for (int r = 0; r < 4; ++r) {
      const int row = rb * 64 + mf * 16 + kg * 4 + r;
      const float gi = acc1[mf][0][r] + acc2[mf][0][r] + b4[0];
      const float gg = acc1[mf][1][r] + acc2[mf][1][r] + b4[1];
      const float gf = acc1[mf][2][r] + acc2[mf][2][r] + b4[2];
      const float go = acc1[mf][3][r] + acc2[mf][3][r] + b4[3];
      const float c0v = c0[(size_t)row * 256 + hcol];
      const float c1v = sigf(gf) * c0v + sigf(gi) * tanhf(gg);
      const float h1v = sigf(go) * tanhf(c1v);
      d_out[(size_t)row * 256 + hcol]  = h1v;
      out_c1[(size_t)row * 256 + hcol] = c1v;
    }
}

// ---------------------------------------------------------------------------
extern "C" void kernel_launch(void* const* d_in, const int* in_sizes, int n_in,
                              void* d_out, int out_size, void* d_ws, size_t ws_size,
                              hipStream_t stream)
{
  (void)in_sizes; (void)n_in; (void)out_size; (void)ws_size;
  const float* x       = (const float*)d_in[0];
  const float* h0      = (const float*)d_in[1];
  const float* c0      = (const float*)d_in[2];
  const float* hhat0   = (const float*)d_in[3];
  const float* chat0   = (const float*)d_in[4];
  const float* hweight = (const float*)d_in[5];
  const float* hbias   = (const float*)d_in[6];
  const float* zw_h    = (const float*)d_in[7];
  const float* zw_x    = (const float*)d_in[8];
  const float* zw_b    = (const float*)d_in[9];
  const float* zb_h    = (const float*)d_in[10];
  const float* zb_x    = (const float*)d_in[11];
  const float* dw_h    = (const float*)d_in[12];
  const float* dw_x    = (const float*)d_in[13];
  const float* dw_b    = (const float*)d_in[14];
  const float* weight  = (const float*)d_in[15];
  const float* bias    = (const float*)d_in[16];

  // workspace layout (bytes, 16B-aligned); total ~86 MB
  char* wsb = (char*)d_ws;
  u16*   abuf    = (u16*)(wsb + 0);              // B*512*2   = 67108864
  u16*   hbuf    = (u16*)(wsb + 67108864);       // B*128*2   = 16777216
  u16*   hw_ts   = (u16*)(wsb + 83886080);       // 2*8*16384*2 = 524288
  u16*   w_ts    = (u16*)(wsb + 84410368);       // 4*6*16384*2 = 786432
  u16*   whp_ts  = (u16*)(wsb + 85196800);       // 4*2*16384*2 = 262144
  u16*   wxp_ts  = (u16*)(wsb + 85458944);
  u16*   wbp_ts  = (u16*)(wsb + 85721088);
  float* hbias_r = (float*)(wsb + 85983232);     // 512*4
  float* bias_r  = (float*)(wsb + 85985280);     // 1024*4
  float* bhp_r   = (float*)(wsb + 85989376);     // 1024*4
  float* bxp_r   = (float*)(wsb + 85993472);     // 1024*4

  hlstm_pre<<<dim3(4608), dim3(256), 0, stream>>>(
      hhat0, h0, x, abuf,
      hweight, hbias, zw_h, zw_x, zw_b, zb_h, zb_x, dw_h, dw_x, dw_b, weight, bias,
      hw_ts, hbias_r, w_ts, bias_r, whp_ts, wxp_ts, wbp_ts, bhp_r, bxp_r);

  hlstm_k1<<<dim3(1024, 2), dim3(256), 0, stream>>>(
      abuf, chat0, hw_ts, hbias_r, (float*)d_out, hbuf);

  hlstm_k2<<<dim3(1024, 4), dim3(256), 0, stream>>>(
      abuf, hbuf, c0, w_ts, bias_r, whp_ts, wxp_ts, wbp_ts, bhp_r, bxp_r, (float*)d_out);
}

// Round 4
// 474.378 us; speedup vs baseline: 1.2696x; 1.0338x over previous
//
#include <hip/hip_runtime.h>

// HyperLSTMCell on MI355X (gfx950).  B=65536, D=128, H=256, Z=128, E=16.
// All inputs/outputs f32; internal GEMMs bf16 MFMA (16x16x32).
//
// Pipeline:
//   pre  : [fused] cast abuf[B][512] bf16 = [hhat0|h0|x]  +  weight prep
//          (gate-gathered virtual col order v = hb*256 + gate*64 + hh, pre-swizzled
//           LDS images; zw->dw fold to dense 128x1024 Wh'/Wx'/Wb' + bias folds)
//   k1   : gh = abuf@hweight + hbias ; hyper LSTM -> hhat1,chat1 (f32) + hbuf (bf16)
//   k2   : acc1 = [h0|x]@weight (K=384); accH = hbuf@Wh'; acc1 *= accH+bh';
//          accX = hbuf@Wx'; acc1 *= accX+bx'; accB = hbuf@Wb';
//          g = acc1 + accB + bias ; LSTM -> h1,c1
//
// k1/k2 K-loop structure (T3+T4): triple-buffered LDS (A and B), raw s_barrier +
// counted `s_waitcnt vmcnt(10)` (never 0 in steady state) so each step's 10
// global_load_lds ride 2 full steps across barriers (~1200 cyc > 900 cyc HBM).
// XCD sibling swizzle: blocks sharing A-rows get consecutive same-XCD slots.
//
// d_out (f32): h1 [B,256] | c1 [B,256] | hhat1 [B,128] | chat1 [B,128]

typedef unsigned short u16;
typedef __attribute__((ext_vector_type(8))) short bf16x8;   // 8 bf16 (4 VGPRs)
typedef __attribute__((ext_vector_type(4))) float f32x4;

#define BATCH 65536

__device__ __forceinline__ u16 f2b(float f) {           // f32 -> bf16 bits, RNE
  unsigned u = __float_as_uint(f);
  u += 0x7fffu + ((u >> 16) & 1u);
  return (u16)(u >> 16);
}
__device__ __forceinline__ float sigf(float x) { return 1.0f / (1.0f + __expf(-x)); }
// LDS XOR swizzle for [row][64] bf16 tiles (G4: breaks the 128B-row-stride conflict).
__device__ __forceinline__ int swz(int r, int c) { return r * 64 + (c ^ ((r & 7) << 3)); }

// counted-vmcnt pipeline barriers (T4): wait until <=N VMEM outstanding, then
// raw barrier (NO compiler vmcnt(0) drain), then scheduler fence (rule #18).
__device__ __forceinline__ void wait10_bar() {
  asm volatile("s_waitcnt vmcnt(10)" ::: "memory");
  __builtin_amdgcn_s_barrier();
  __builtin_amdgcn_sched_barrier(0);
}
__device__ __forceinline__ void wait0_bar() {
  asm volatile("s_waitcnt vmcnt(0)" ::: "memory");
  __builtin_amdgcn_s_barrier();
  __builtin_amdgcn_sched_barrier(0);
}

// async global->LDS, 16B per lane (m97: global_load_lds_dwordx4)
__device__ __forceinline__ void gl_lds16(const u16* g, u16* l) {
  __builtin_amdgcn_global_load_lds(
      (const __attribute__((address_space(1))) void*)g,
      (__attribute__((address_space(3))) void*)l, 16, 0, 0);
}
// stage 64-row x 64-col A-tile from row-major bf16 (row stride ldk elems) into the
// swizzled LDS image: linear LDS dest + XOR-permuted GLOBAL source chunks (m173).
__device__ __forceinline__ void stageA(const u16* base, int ldk, u16* lA, int t) {
  const int r = t >> 3, q = t & 7, wid = t >> 6;
  const int qs = (q ^ (r & 7)) << 3;                 // (r+32)&7 == r&7
  gl_lds16(base + (size_t)r * ldk + qs, lA + wid * 512);
  gl_lds16(base + (size_t)(r + 32) * ldk + qs, lA + 2048 + wid * 512);
}
// stage 256x64 pre-swizzled B image (linear copy)
__device__ __forceinline__ void stageB(const u16* tile, u16* lB, int t) {
  const int wid = t >> 6;
#pragma unroll
  for (int i = 0; i < 8; ++i)
    gl_lds16(tile + ((size_t)i * 256 + t) * 8, lB + i * 2048 + wid * 512);
}

// ---------------------------------------------------------------------------
// pre: fused input-cast + weight prep.
// ---------------------------------------------------------------------------
__global__ __launch_bounds__(256) void hlstm_pre(
    const float* __restrict__ hhat0, const float* __restrict__ h0,
    const float* __restrict__ x, u16* __restrict__ abuf,
    const float* __restrict__ hweight, const float* __restrict__ hbias,
    const float* __restrict__ zw_h, const float* __restrict__ zw_x, const float* __restrict__ zw_b,
    const float* __restrict__ zb_h, const float* __restrict__ zb_x,
    const float* __restrict__ dw_h, const float* __restrict__ dw_x, const float* __restrict__ dw_b,
    const float* __restrict__ weight, const float* __restrict__ bias,
    u16* __restrict__ hw_ts, float* __restrict__ hbias_r,
    u16* __restrict__ w_ts,  float* __restrict__ bias_r,
    u16* __restrict__ whp_ts, u16* __restrict__ wxp_ts, u16* __restrict__ wbp_ts,
    float* __restrict__ bhp_r, float* __restrict__ bxp_r)
{
  if (blockIdx.x < 4096) {
    // ---- cast part: abuf[B][512] = bf16([hhat0 | h0 | x])
    const size_t stride = (size_t)4096 * 256;
    for (size_t i = (size_t)blockIdx.x * 256 + threadIdx.x;
         i < (size_t)BATCH * 64; i += stride) {
      const size_t b = i >> 6; const int c = (int)(i & 63);
      const float* src;
      if (c < 16)      src = hhat0 + b * 128 + c * 8;
      else if (c < 48) src = h0 + b * 256 + (size_t)(c - 16) * 8;
      else             src = x + b * 128 + (size_t)(c - 48) * 8;
      float4 v0 = ((const float4*)src)[0];
      float4 v1 = ((const float4*)src)[1];
      alignas(16) u16 o[8] = {f2b(v0.x), f2b(v0.y), f2b(v0.z), f2b(v0.w),
                              f2b(v1.x), f2b(v1.y), f2b(v1.z), f2b(v1.w)};
      *(uint4*)(abuf + i * 8) = *(const uint4*)o;
    }
    return;
  }
  // ---- prep part
  const int tid = (blockIdx.x - 4096) * 256 + threadIdx.x;
  const int nt  = 512 * 256;

  // hw_ts: [hb(2)][ks(8)] tiles of [n=256][kk=64] at swizzled positions
  for (int i = tid; i < 2 * 8 * 16384; i += nt) {
    int tile = i >> 14, idx = i & 16383;
    int hb = tile >> 3, ks = tile & 7;
    int n = idx >> 6, kk = (idx & 63) ^ ((n & 7) << 3);
    int gate = (n >> 6) & 3, hh = n & 63;
    int k = ks * 64 + kk;
    hw_ts[i] = f2b(hweight[k * 512 + gate * 128 + hb * 64 + hh]);
  }
  // w_ts: [hb(4)][ks(6)] tiles
  for (int i = tid; i < 4 * 6 * 16384; i += nt) {
    int tile = i >> 14, idx = i & 16383;
    int hb = tile / 6, ks = tile % 6;
    int n = idx >> 6, kk = (idx & 63) ^ ((n & 7) << 3);
    int gate = (n >> 6) & 3, hh = n & 63;
    int k = ks * 64 + kk;
    w_ts[i] = f2b(weight[k * 1024 + gate * 256 + hb * 64 + hh]);
  }
  // folded hyper matrices: W'[k][(g,h)] = sum_e zw[k, g*16+e] * dw[g,e,h]
  for (int i = tid; i < 3 * 4 * 2 * 16384; i += nt) {
    int mat = i / (8 * 16384), rem = i % (8 * 16384);
    int tile = rem >> 14, idx = rem & 16383;
    int hb = tile >> 1, ks = tile & 1;
    int n = idx >> 6, kk = (idx & 63) ^ ((n & 7) << 3);
    int g = n >> 6, hh = n & 63;
    int k = ks * 64 + kk;
    int h = hb * 64 + hh;
    const float* zw = (mat == 0) ? zw_h : (mat == 1) ? zw_x : zw_b;
    const float* dw = (mat == 0) ? dw_h : (mat == 1) ? dw_x : dw_b;
    float s = 0.f;
#pragma unroll
    for (int e = 0; e < 16; ++e)
      s += zw[k * 64 + g * 16 + e] * dw[g * 4096 + e * 256 + h];
    u16* dst = (mat == 0) ? whp_ts : (mat == 1) ? wxp_ts : wbp_ts;
    dst[rem] = f2b(s);
  }
  // bias folds (virtual order hb*256 + g*64 + hh)
  for (int i = tid; i < 1024; i += nt) {
    int hb = i >> 8, g = (i >> 6) & 3, hh = i & 63;
    int h = hb * 64 + hh;
    float sh = 0.f, sx = 0.f;
#pragma unroll
    for (int e = 0; e < 16; ++e) {
      sh += zb_h[g * 16 + e] * dw_h[g * 4096 + e * 256 + h];
      sx += zb_x[g * 16 + e] * dw_x[g * 4096 + e * 256 + h];
    }
    bhp_r[i] = sh; bxp_r[i] = sx;
    bias_r[i] = bias[g * 256 + h];
  }
  for (int i = tid; i < 512; i += nt) {
    int gate = (i >> 6) & 3, hb = i >> 8, hh = i & 63;
    hbias_r[i] = hbias[gate * 128 + hb * 64 + hh];
  }
}

// ---------------------------------------------------------------------------
// k1: hyper GEMM (K=512, 8 steps) + hyper LSTM. 2048 blocks x 256 threads.
// Triple-buffered pipeline, counted vmcnt.
// ---------------------------------------------------------------------------
__global__ __launch_bounds__(256) void hlstm_k1(
    const u16* __restrict__ abuf, const float* __restrict__ chat0,
    const u16* __restrict__ hw_ts, const float* __restrict__ hbias_r,
    float* __restrict__ d_out, u16* __restrict__ hbuf)
{
  __shared__ alignas(16) u16 lA[3][64 * 64];
  __shared__ alignas(16) u16 lB[3][256 * 64];
  // XCD sibling swizzle: 2 hb-siblings of each rb on the same XCD, adjacent slots.
  const int f = blockIdx.x;                 // 0..2047
  const int xcd = f & 7, s2 = f >> 3;       // s2: 0..255
  const int rb = xcd * 128 + (s2 >> 1), hb = s2 & 1;
  const int t = threadIdx.x;
  const int lane = t & 63, wc = t >> 6;
  const int lr = lane & 15, kg = lane >> 4;

  f32x4 acc[4][4];
  const f32x4 zzero = {0.f, 0.f, 0.f, 0.f};
#pragma unroll
  for (int mf = 0; mf < 4; ++mf)
#pragma unroll
    for (int g = 0; g < 4; ++g) acc[mf][g] = zzero;

  const u16* arow = abuf + (size_t)rb * 64 * 512;

  // prologue: stage steps 0 and 1
  stageB(hw_ts + (size_t)(hb * 8 + 0) * 16384, lB[0], t);
  stageA(arow + 0 * 64, 512, lA[0], t);
  stageB(hw_ts + (size_t)(hb * 8 + 1) * 16384, lB[1], t);
  stageA(arow + 1 * 64, 512, lA[1], t);
  wait10_bar();

#pragma unroll
  for (int ks = 0; ks < 8; ++ks) {
    if (ks < 6) {
      stageB(hw_ts + (size_t)(hb * 8 + ks + 2) * 16384, lB[(ks + 2) % 3], t);
      stageA(arow + (ks + 2) * 64, 512, lA[(ks + 2) % 3], t);
    }
    const u16* cA = lA[ks % 3];
    const u16* cB = lB[ks % 3];
#pragma unroll
    for (int h = 0; h < 2; ++h) {
      bf16x8 bfr[4];
#pragma unroll
      for (int g = 0; g < 4; ++g)
        bfr[g] = *(const bf16x8*)&cB[swz(g * 64 + wc * 16 + lr, h * 32 + kg * 8)];
#pragma unroll
      for (int mf = 0; mf < 4; ++mf) {
        bf16x8 afr = *(const bf16x8*)&cA[swz(mf * 16 + lr, h * 32 + kg * 8)];
#pragma unroll
        for (int g = 0; g < 4; ++g)
          acc[mf][g] = __builtin_amdgcn_mfma_f32_16x16x32_bf16(afr, bfr[g], acc[mf][g], 0, 0, 0);
      }
    }
    if (ks < 6) wait10_bar();
    else if (ks == 6) wait0_bar();
  }

  float hb4[4];
#pragma unroll
  for (int g = 0; g < 4; ++g) hb4[g] = hbias_r[hb * 256 + g * 64 + wc * 16 + lr];
  const int zc = hb * 64 + wc * 16 + lr;
  float* out_hh = d_out + (size_t)BATCH * 512;
  float* out_ch = d_out + (size_t)BATCH * 640;
#pragma unroll
  for (int mf = 0; mf < 4; ++mf)
#pragma unroll
    for (int r = 0; r < 4; ++r) {
      const int row = rb * 64 + mf * 16 + kg * 4 + r;
      const float gi = acc[mf][0][r] + hb4[0];
      const float gg = acc[mf][1][r] + hb4[1];
      const float gf = acc[mf][2][r] + hb4[2];
      const float go = acc[mf][3][r] + hb4[3];
      const float c0v = chat0[(size_t)row * 128 + zc];
      const float c1v = sigf(gf) * c0v + sigf(gi) * tanhf(gg);
      const float h1v = sigf(go) * tanhf(c1v);
      out_hh[(size_t)row * 128 + zc] = h1v;
      out_ch[(size_t)row * 128 + zc] = c1v;
      hbuf[(size_t)row * 128 + zc] = f2b(h1v);
    }
}

// ---------------------------------------------------------------------------
// k2: 12 flat K-steps — 6 x main GEMM (K=384) then 3 x 2 folded hyper (K=128) —
// triple-buffered counted-vmcnt pipeline. 4096 blocks x 256 threads.
// ---------------------------------------------------------------------------
__global__ __launch_bounds__(256) void hlstm_k2(
    const u16* __restrict__ abuf, const u16* __restrict__ hbuf,
    const float* __restrict__ c0,
    const u16* __restrict__ w_ts, const float* __restrict__ bias_r,
    const u16* __restrict__ whp_ts, const u16* __restrict__ wxp_ts, const u16* __restrict__ wbp_ts,
    const float* __restrict__ bhp_r, const float* __restrict__ bxp_r,
    float* __restrict__ d_out)
{
  __shared__ alignas(16) u16 lA[3][64 * 64];
  __shared__ alignas(16) u16 lB[3][256 * 64];
  // XCD sibling swizzle: 4 hb-siblings of each rb on the same XCD, adjacent slots.
  const int f = blockIdx.x;                 // 0..4095
  const int xcd = f & 7, s4 = f >> 3;       // s4: 0..511
  const int rb = xcd * 128 + (s4 >> 2), hb = s4 & 3;
  const int t = threadIdx.x;
  const int lane = t & 63, wc = t >> 6;
  const int lr = lane & 15, kg = lane >> 4;

  const u16* amain = abuf + (size_t)rb * 64 * 512 + 128;   // [h0|x] cols, ld 512
  const u16* ahyp  = hbuf + (size_t)rb * 64 * 128;         // ld 128

  auto aptr = [&](int s) -> const u16* {
    return (s < 6) ? (amain + s * 64) : (ahyp + ((s - 6) & 1) * 64);
  };
  auto aldk = [&](int s) -> int { return (s < 6) ? 512 : 128; };
  auto bptr = [&](int s) -> const u16* {
    if (s < 6) return w_ts + (size_t)(hb * 6 + s) * 16384;
    const int ph = (s - 6) >> 1, ks = (s - 6) & 1;
    const u16* wp = (ph == 0) ? whp_ts : (ph == 1) ? wxp_ts : wbp_ts;
    return wp + (size_t)(hb * 2 + ks) * 16384;
  };

  f32x4 acc1[4][4], acc2[4][4];
  const f32x4 zzero = {0.f, 0.f, 0.f, 0.f};
#pragma unroll
  for (int mf = 0; mf < 4; ++mf)
#pragma unroll
    for (int g = 0; g < 4; ++g) acc1[mf][g] = zzero;

  float b4[4], bh4[4], bx4[4];
#pragma unroll
  for (int g = 0; g < 4; ++g) {
    b4[g]  = bias_r[hb * 256 + g * 64 + wc * 16 + lr];
    bh4[g] = bhp_r[hb * 256 + g * 64 + wc * 16 + lr];
    bx4[g] = bxp_r[hb * 256 + g * 64 + wc * 16 + lr];
  }

  // prologue: stage steps 0 and 1
  stageB(bptr(0), lB[0], t);
  stageA(aptr(0), aldk(0), lA[0], t);
  stageB(bptr(1), lB[1], t);
  stageA(aptr(1), aldk(1), lA[1], t);
  wait10_bar();

#pragma unroll
  for (int s = 0; s < 12; ++s) {
    if (s < 10) {
      stageB(bptr(s + 2), lB[(s + 2) % 3], t);
      stageA(aptr(s + 2), aldk(s + 2), lA[(s + 2) % 3], t);
    }
    if (s == 6 || s == 8 || s == 10) {
#pragma unroll
      for (int mf = 0; mf < 4; ++mf)
#pragma unroll
        for (int g = 0; g < 4; ++g) acc2[mf][g] = zzero;
    }
    const u16* cA = lA[s % 3];
    const u16* cB = lB[s % 3];
#pragma unroll
    for (int h = 0; h < 2; ++h) {
      bf16x8 bfr[4];
#pragma unroll
      for (int g = 0; g < 4; ++g)
        bfr[g] = *(const bf16x8*)&cB[swz(g * 64 + wc * 16 + lr, h * 32 + kg * 8)];
#pragma unroll
      for (int mf = 0; mf < 4; ++mf) {
        bf16x8 afr = *(const bf16x8*)&cA[swz(mf * 16 + lr, h * 32 + kg * 8)];
#pragma unroll
        for (int g = 0; g < 4; ++g) {
          if (s < 6)
            acc1[mf][g] = __builtin_amdgcn_mfma_f32_16x16x32_bf16(afr, bfr[g], acc1[mf][g], 0, 0, 0);
          else
            acc2[mf][g] = __builtin_amdgcn_mfma_f32_16x16x32_bf16(afr, bfr[g], acc2[mf][g], 0, 0, 0);
        }
      }
    }
    if (s == 7) {        // acc1 *= d_yh
#pragma unroll
      for (int mf = 0; mf < 4; ++mf)
#pragma unroll
        for (int g = 0; g < 4; ++g)
#pragma unroll
          for (int r = 0; r < 4; ++r) acc1[mf][g][r] *= (acc2[mf][g][r] + bh4[g]);
    } else if (s == 9) { // acc1 *= d_yx
#pragma unroll
      for (int mf = 0; mf < 4; ++mf)
#pragma unroll
        for (int g = 0; g < 4; ++g)
#pragma unroll
          for (int r = 0; r < 4; ++r) acc1[mf][g][r] *= (acc2[mf][g][r] + bx4[g]);
    }
    if (s < 10) wait10_bar();
    else if (s == 10) wait0_bar();
  }

  // ---- epilogue: main LSTM cell (acc2 holds d_yb)
  const int hcol = hb * 64 + wc * 16 + lr;
  float* out_c1 = d_out + (size_t)BATCH * 256;
#pragma unroll
  for (int mf = 0; mf < 4; ++mf)
#pragma unroll
    for (int r = 0; r < 4; ++r) {
      const int row = rb * 64 + mf * 16 + kg * 4 + r;
      const float gi = acc1[mf][0][r] + acc2[mf][0][r] + b4[0];
      const float gg = acc1[mf][1][r] + acc2[mf][1][r] + b4[1];
      const float gf = acc1[mf][2][r] + acc2[mf][2][r] + b4[2];
      const float go = acc1[mf][3][r] + acc2[mf][3][r] + b4[3];
      const float c0v = c0[(size_t)row * 256 + hcol];
      const float c1v = sigf(gf) * c0v + sigf(gi) * tanhf(gg);
      const float h1v = sigf(go) * tanhf(c1v);
      d_out[(size_t)row * 256 + hcol]  = h1v;
      out_c1[(size_t)row * 256 + hcol] = c1v;
    }
}

// ---------------------------------------------------------------------------
extern "C" void kernel_launch(void* const* d_in, const int* in_sizes, int n_in,
                              void* d_out, int out_size, void* d_ws, size_t ws_size,
                              hipStream_t stream)
{
  (void)in_sizes; (void)n_in; (void)out_size; (void)ws_size;
  const float* x       = (const float*)d_in[0];
  const float* h0      = (const float*)d_in[1];
  const float* c0      = (const float*)d_in[2];
  const float* hhat0   = (const float*)d_in[3];
  const float* chat0   = (const float*)d_in[4];
  const float* hweight = (const float*)d_in[5];
  const float* hbias   = (const float*)d_in[6];
  const float* zw_h    = (const float*)d_in[7];
  const float* zw_x    = (const float*)d_in[8];
  const float* zw_b    = (const float*)d_in[9];
  const float* zb_h    = (const float*)d_in[10];
  const float* zb_x    = (const float*)d_in[11];
  const float* dw_h    = (const float*)d_in[12];
  const float* dw_x    = (const float*)d_in[13];
  const float* dw_b    = (const float*)d_in[14];
  const float* weight  = (const float*)d_in[15];
  const float* bias    = (const float*)d_in[16];

  // workspace layout (bytes, 16B-aligned); total ~86 MB
  char* wsb = (char*)d_ws;
  u16*   abuf    = (u16*)(wsb + 0);              // B*512*2   = 67108864
  u16*   hbuf    = (u16*)(wsb + 67108864);       // B*128*2   = 16777216
  u16*   hw_ts   = (u16*)(wsb + 83886080);       // 2*8*16384*2 = 524288
  u16*   w_ts    = (u16*)(wsb + 84410368);       // 4*6*16384*2 = 786432
  u16*   whp_ts  = (u16*)(wsb + 85196800);       // 4*2*16384*2 = 262144
  u16*   wxp_ts  = (u16*)(wsb + 85458944);
  u16*   wbp_ts  = (u16*)(wsb + 85721088);
  float* hbias_r = (float*)(wsb + 85983232);     // 512*4
  float* bias_r  = (float*)(wsb + 85985280);     // 1024*4
  float* bhp_r   = (float*)(wsb + 85989376);     // 1024*4
  float* bxp_r   = (float*)(wsb + 85993472);     // 1024*4

  hlstm_pre<<<dim3(4608), dim3(256), 0, stream>>>(
      hhat0, h0, x, abuf,
      hweight, hbias, zw_h, zw_x, zw_b, zb_h, zb_x, dw_h, dw_x, dw_b, weight, bias,
      hw_ts, hbias_r, w_ts, bias_r, whp_ts, wxp_ts, wbp_ts, bhp_r, bxp_r);

  hlstm_k1<<<dim3(2048), dim3(256), 0, stream>>>(
      abuf, chat0, hw_ts, hbias_r, (float*)d_out, hbuf);

  hlstm_k2<<<dim3(4096), dim3(256), 0, stream>>>(
      abuf, hbuf, c0, w_ts, bias_r, whp_ts, wxp_ts, wbp_ts, bhp_r, bxp_r, (float*)d_out);
}

// Round 5
// 441.657 us; speedup vs baseline: 1.3637x; 1.0741x over previous
//
#include <hip/hip_runtime.h>

// HyperLSTMCell on MI355X (gfx950).  B=65536, D=128, H=256, Z=128, E=16.
// All inputs/outputs f32; internal GEMMs bf16 MFMA (16x16x32).
//
// Pipeline:
//   pre  : [fused] cast abuf[B][512] bf16 = [hhat0|h0|x]  +  weight prep
//          (gate-gathered virtual col order v = hb*256 + gate*64 + hh, pre-swizzled
//           LDS images; zw->dw fold to dense 128x1024 Wh'/Wx'/Wb' + bias folds)
//   k1   : gh = abuf@hweight + hbias ; hyper LSTM -> hhat1,chat1 (f32) + hbuf (bf16)
//   k2   : acc1 = [h0|x]@weight (K=384); accH = hbuf@Wh'; acc1 *= accH+bh';
//          accX = hbuf@Wx'; acc1 *= accX+bx'; accB = hbuf@Wb';
//          g = acc1 + accB + bias ; LSTM -> h1,c1
//
// r5 structure: 512-thread blocks (8 waves = 2 waves/SIMD for TLP), 128x256 tile
// (waves 2M x 4N, per-wave acc unchanged), triple-buffered LDS 144 KB, raw
// s_barrier + counted `s_waitcnt vmcnt(6)` (loads ride 2 steps across barriers).
// XCD sibling swizzle on blockIdx.
//
// d_out (f32): h1 [B,256] | c1 [B,256] | hhat1 [B,128] | chat1 [B,128]

typedef unsigned short u16;
typedef __attribute__((ext_vector_type(8))) short bf16x8;   // 8 bf16 (4 VGPRs)
typedef __attribute__((ext_vector_type(4))) float f32x4;

#define BATCH 65536

__device__ __forceinline__ u16 f2b(float f) {           // f32 -> bf16 bits, RNE
  unsigned u = __float_as_uint(f);
  u += 0x7fffu + ((u >> 16) & 1u);
  return (u16)(u >> 16);
}
__device__ __forceinline__ float sigf(float x) { return 1.0f / (1.0f + __expf(-x)); }
// LDS XOR swizzle for [row][64] bf16 tiles (G4: breaks the 128B-row-stride conflict).
__device__ __forceinline__ int swz(int r, int c) { return r * 64 + (c ^ ((r & 7) << 3)); }

// counted-vmcnt pipeline barriers (T4): wait until <=N VMEM outstanding, then
// raw barrier (NO compiler vmcnt(0) drain), then scheduler fence (rule #18).
__device__ __forceinline__ void wait6_bar() {
  asm volatile("s_waitcnt vmcnt(6)" ::: "memory");
  __builtin_amdgcn_s_barrier();
  __builtin_amdgcn_sched_barrier(0);
}
__device__ __forceinline__ void wait0_bar() {
  asm volatile("s_waitcnt vmcnt(0)" ::: "memory");
  __builtin_amdgcn_s_barrier();
  __builtin_amdgcn_sched_barrier(0);
}

// async global->LDS, 16B per lane (m97: global_load_lds_dwordx4)
__device__ __forceinline__ void gl_lds16(const u16* g, u16* l) {
  __builtin_amdgcn_global_load_lds(
      (const __attribute__((address_space(1))) void*)g,
      (__attribute__((address_space(3))) void*)l, 16, 0, 0);
}
// stage 128-row x 64-col A-tile (16 KB) from row-major bf16 (stride ldk) into the
// swizzled LDS image: linear LDS dest + XOR-permuted GLOBAL source chunks (m173).
// 512 threads x 2 chunks of 16B.
__device__ __forceinline__ void stageA128(const u16* base, int ldk, u16* lA, int t) {
  const int wid = t >> 6, q = t & 7;
#pragma unroll
  for (int i = 0; i < 2; ++i) {
    const int r = (i * 512 + t) >> 3;
    gl_lds16(base + (size_t)r * ldk + ((q ^ (r & 7)) << 3), lA + i * 4096 + wid * 512);
  }
}
// stage 256x64 pre-swizzled B image (32 KB, linear copy), 512 threads x 4 chunks.
__device__ __forceinline__ void stageB256(const u16* tile, u16* lB, int t) {
  const int wid = t >> 6;
#pragma unroll
  for (int i = 0; i < 4; ++i)
    gl_lds16(tile + ((size_t)i * 512 + t) * 8, lB + i * 4096 + wid * 512);
}

// ---------------------------------------------------------------------------
// pre: fused input-cast + weight prep.
// ---------------------------------------------------------------------------
__global__ __launch_bounds__(256) void hlstm_pre(
    const float* __restrict__ hhat0, const float* __restrict__ h0,
    const float* __restrict__ x, u16* __restrict__ abuf,
    const float* __restrict__ hweight, const float* __restrict__ hbias,
    const float* __restrict__ zw_h, const float* __restrict__ zw_x, const float* __restrict__ zw_b,
    const float* __restrict__ zb_h, const float* __restrict__ zb_x,
    const float* __restrict__ dw_h, const float* __restrict__ dw_x, const float* __restrict__ dw_b,
    const float* __restrict__ weight, const float* __restrict__ bias,
    u16* __restrict__ hw_ts, float* __restrict__ hbias_r,
    u16* __restrict__ w_ts,  float* __restrict__ bias_r,
    u16* __restrict__ whp_ts, u16* __restrict__ wxp_ts, u16* __restrict__ wbp_ts,
    float* __restrict__ bhp_r, float* __restrict__ bxp_r)
{
  if (blockIdx.x < 4096) {
    // ---- cast part: abuf[B][512] = bf16([hhat0 | h0 | x])
    const size_t stride = (size_t)4096 * 256;
    for (size_t i = (size_t)blockIdx.x * 256 + threadIdx.x;
         i < (size_t)BATCH * 64; i += stride) {
      const size_t b = i >> 6; const int c = (int)(i & 63);
      const float* src;
      if (c < 16)      src = hhat0 + b * 128 + c * 8;
      else if (c < 48) src = h0 + b * 256 + (size_t)(c - 16) * 8;
      else             src = x + b * 128 + (size_t)(c - 48) * 8;
      float4 v0 = ((const float4*)src)[0];
      float4 v1 = ((const float4*)src)[1];
      alignas(16) u16 o[8] = {f2b(v0.x), f2b(v0.y), f2b(v0.z), f2b(v0.w),
                              f2b(v1.x), f2b(v1.y), f2b(v1.z), f2b(v1.w)};
      *(uint4*)(abuf + i * 8) = *(const uint4*)o;
    }
    return;
  }
  // ---- prep part
  const int tid = (blockIdx.x - 4096) * 256 + threadIdx.x;
  const int nt  = 512 * 256;

  // hw_ts: [hb(2)][ks(8)] tiles of [n=256][kk=64] at swizzled positions
  for (int i = tid; i < 2 * 8 * 16384; i += nt) {
    int tile = i >> 14, idx = i & 16383;
    int hb = tile >> 3, ks = tile & 7;
    int n = idx >> 6, kk = (idx & 63) ^ ((n & 7) << 3);
    int gate = (n >> 6) & 3, hh = n & 63;
    int k = ks * 64 + kk;
    hw_ts[i] = f2b(hweight[k * 512 + gate * 128 + hb * 64 + hh]);
  }
  // w_ts: [hb(4)][ks(6)] tiles
  for (int i = tid; i < 4 * 6 * 16384; i += nt) {
    int tile = i >> 14, idx = i & 16383;
    int hb = tile / 6, ks = tile % 6;
    int n = idx >> 6, kk = (idx & 63) ^ ((n & 7) << 3);
    int gate = (n >> 6) & 3, hh = n & 63;
    int k = ks * 64 + kk;
    w_ts[i] = f2b(weight[k * 1024 + gate * 256 + hb * 64 + hh]);
  }
  // folded hyper matrices: W'[k][(g,h)] = sum_e zw[k, g*16+e] * dw[g,e,h]
  for (int i = tid; i < 3 * 4 * 2 * 16384; i += nt) {
    int mat = i / (8 * 16384), rem = i % (8 * 16384);
    int tile = rem >> 14, idx = rem & 16383;
    int hb = tile >> 1, ks = tile & 1;
    int n = idx >> 6, kk = (idx & 63) ^ ((n & 7) << 3);
    int g = n >> 6, hh = n & 63;
    int k = ks * 64 + kk;
    int h = hb * 64 + hh;
    const float* zw = (mat == 0) ? zw_h : (mat == 1) ? zw_x : zw_b;
    const float* dw = (mat == 0) ? dw_h : (mat == 1) ? dw_x : dw_b;
    float s = 0.f;
#pragma unroll
    for (int e = 0; e < 16; ++e)
      s += zw[k * 64 + g * 16 + e] * dw[g * 4096 + e * 256 + h];
    u16* dst = (mat == 0) ? whp_ts : (mat == 1) ? wxp_ts : wbp_ts;
    dst[rem] = f2b(s);
  }
  // bias folds (virtual order hb*256 + g*64 + hh)
  for (int i = tid; i < 1024; i += nt) {
    int hb = i >> 8, g = (i >> 6) & 3, hh = i & 63;
    int h = hb * 64 + hh;
    float sh = 0.f, sx = 0.f;
#pragma unroll
    for (int e = 0; e < 16; ++e) {
      sh += zb_h[g * 16 + e] * dw_h[g * 4096 + e * 256 + h];
      sx += zb_x[g * 16 + e] * dw_x[g * 4096 + e * 256 + h];
    }
    bhp_r[i] = sh; bxp_r[i] = sx;
    bias_r[i] = bias[g * 256 + h];
  }
  for (int i = tid; i < 512; i += nt) {
    int gate = (i >> 6) & 3, hb = i >> 8, hh = i & 63;
    hbias_r[i] = hbias[gate * 128 + hb * 64 + hh];
  }
}

// ---------------------------------------------------------------------------
// k1: hyper GEMM (K=512, 8 steps) + hyper LSTM. 1024 blocks x 512 threads.
// 128x256 tile, 8 waves (2M x 4N), triple-buffered counted-vmcnt pipeline.
// ---------------------------------------------------------------------------
__global__ __launch_bounds__(512, 2) void hlstm_k1(
    const u16* __restrict__ abuf, const float* __restrict__ chat0,
    const u16* __restrict__ hw_ts, const float* __restrict__ hbias_r,
    float* __restrict__ d_out, u16* __restrict__ hbuf)
{
  __shared__ alignas(16) u16 lA[3][128 * 64];
  __shared__ alignas(16) u16 lB[3][256 * 64];
  // XCD sibling swizzle: 2 hb-siblings of each rb adjacent on the same XCD.
  const int f = blockIdx.x;                 // 0..1023
  const int xcd = f & 7, s2 = f >> 3;       // s2: 0..127
  const int rb = xcd * 64 + (s2 >> 1), hb = s2 & 1;
  const int t = threadIdx.x;
  const int lane = t & 63, w = t >> 6;
  const int wm = w >> 2, wn = w & 3;        // wave tile: rows wm*64, cols wn*16/gate
  const int lr = lane & 15, kg = lane >> 4;

  f32x4 acc[4][4];
  const f32x4 zzero = {0.f, 0.f, 0.f, 0.f};
#pragma unroll
  for (int mf = 0; mf < 4; ++mf)
#pragma unroll
    for (int g = 0; g < 4; ++g) acc[mf][g] = zzero;

  const u16* arow = abuf + (size_t)rb * 128 * 512;

  // prologue: stage steps 0 and 1
  stageB256(hw_ts + (size_t)(hb * 8 + 0) * 16384, lB[0], t);
  stageA128(arow + 0 * 64, 512, lA[0], t);
  stageB256(hw_ts + (size_t)(hb * 8 + 1) * 16384, lB[1], t);
  stageA128(arow + 1 * 64, 512, lA[1], t);
  wait6_bar();

#pragma unroll
  for (int ks = 0; ks < 8; ++ks) {
    if (ks < 6) {
      stageB256(hw_ts + (size_t)(hb * 8 + ks + 2) * 16384, lB[(ks + 2) % 3], t);
      stageA128(arow + (ks + 2) * 64, 512, lA[(ks + 2) % 3], t);
    }
    const u16* cA = lA[ks % 3];
    const u16* cB = lB[ks % 3];
#pragma unroll
    for (int h = 0; h < 2; ++h) {
      bf16x8 bfr[4];
#pragma unroll
      for (int g = 0; g < 4; ++g)
        bfr[g] = *(const bf16x8*)&cB[swz(g * 64 + wn * 16 + lr, h * 32 + kg * 8)];
#pragma unroll
      for (int mf = 0; mf < 4; ++mf) {
        bf16x8 afr = *(const bf16x8*)&cA[swz(wm * 64 + mf * 16 + lr, h * 32 + kg * 8)];
#pragma unroll
        for (int g = 0; g < 4; ++g)
          acc[mf][g] = __builtin_amdgcn_mfma_f32_16x16x32_bf16(afr, bfr[g], acc[mf][g], 0, 0, 0);
      }
    }
    if (ks < 6) wait6_bar();
    else if (ks == 6) wait0_bar();
  }

  float hb4[4];
#pragma unroll
  for (int g = 0; g < 4; ++g) hb4[g] = hbias_r[hb * 256 + g * 64 + wn * 16 + lr];
  const int zc = hb * 64 + wn * 16 + lr;
  float* out_hh = d_out + (size_t)BATCH * 512;
  float* out_ch = d_out + (size_t)BATCH * 640;
#pragma unroll
  for (int mf = 0; mf < 4; ++mf)
#pragma unroll
    for (int r = 0; r < 4; ++r) {
      const int row = rb * 128 + wm * 64 + mf * 16 + kg * 4 + r;
      const float gi = acc[mf][0][r] + hb4[0];
      const float gg = acc[mf][1][r] + hb4[1];
      const float gf = acc[mf][2][r] + hb4[2];
      const float go = acc[mf][3][r] + hb4[3];
      const float c0v = chat0[(size_t)row * 128 + zc];
      const float c1v = sigf(gf) * c0v + sigf(gi) * tanhf(gg);
      const float h1v = sigf(go) * tanhf(c1v);
      out_hh[(size_t)row * 128 + zc] = h1v;
      out_ch[(size_t)row * 128 + zc] = c1v;
      hbuf[(size_t)row * 128 + zc] = f2b(h1v);
    }
}

// ---------------------------------------------------------------------------
// k2: 12 flat K-steps — 6 x main GEMM (K=384) then 3 x 2 folded hyper (K=128) —
// triple-buffered counted-vmcnt pipeline. 2048 blocks x 512 threads.
// ---------------------------------------------------------------------------
__global__ __launch_bounds__(512, 2) void hlstm_k2(
    const u16* __restrict__ abuf, const u16* __restrict__ hbuf,
    const float* __restrict__ c0,
    const u16* __restrict__ w_ts, const float* __restrict__ bias_r,
    const u16* __restrict__ whp_ts, const u16* __restrict__ wxp_ts, const u16* __restrict__ wbp_ts,
    const float* __restrict__ bhp_r, const float* __restrict__ bxp_r,
    float* __restrict__ d_out)
{
  __shared__ alignas(16) u16 lA[3][128 * 64];
  __shared__ alignas(16) u16 lB[3][256 * 64];
  // XCD sibling swizzle: 4 hb-siblings of each rb adjacent on the same XCD.
  const int f = blockIdx.x;                 // 0..2047
  const int xcd = f & 7, s4 = f >> 3;       // s4: 0..255
  const int rb = xcd * 64 + (s4 >> 2), hb = s4 & 3;
  const int t = threadIdx.x;
  const int lane = t & 63, w = t >> 6;
  const int wm = w >> 2, wn = w & 3;
  const int lr = lane & 15, kg = lane >> 4;

  const u16* amain = abuf + (size_t)rb * 128 * 512 + 128;   // [h0|x] cols, ld 512
  const u16* ahyp  = hbuf + (size_t)rb * 128 * 128;         // ld 128

  auto aptr = [&](int s) -> const u16* {
    return (s < 6) ? (amain + s * 64) : (ahyp + ((s - 6) & 1) * 64);
  };
  auto aldk = [&](int s) -> int { return (s < 6) ? 512 : 128; };
  auto bptr = [&](int s) -> const u16* {
    if (s < 6) return w_ts + (size_t)(hb * 6 + s) * 16384;
    const int ph = (s - 6) >> 1, ks = (s - 6) & 1;
    const u16* wp = (ph == 0) ? whp_ts : (ph == 1) ? wxp_ts : wbp_ts;
    return wp + (size_t)(hb * 2 + ks) * 16384;
  };

  f32x4 acc1[4][4], acc2[4][4];
  const f32x4 zzero = {0.f, 0.f, 0.f, 0.f};
#pragma unroll
  for (int mf = 0; mf < 4; ++mf)
#pragma unroll
    for (int g = 0; g < 4; ++g) acc1[mf][g] = zzero;

  float b4[4], bh4[4], bx4[4];
#pragma unroll
  for (int g = 0; g < 4; ++g) {
    b4[g]  = bias_r[hb * 256 + g * 64 + wn * 16 + lr];
    bh4[g] = bhp_r[hb * 256 + g * 64 + wn * 16 + lr];
    bx4[g] = bxp_r[hb * 256 + g * 64 + wn * 16 + lr];
  }

  // prologue: stage steps 0 and 1
  stageB256(bptr(0), lB[0], t);
  stageA128(aptr(0), aldk(0), lA[0], t);
  stageB256(bptr(1), lB[1], t);
  stageA128(aptr(1), aldk(1), lA[1], t);
  wait6_bar();

#pragma unroll
  for (int s = 0; s < 12; ++s) {
    if (s < 10) {
      stageB256(bptr(s + 2), lB[(s + 2) % 3], t);
      stageA128(aptr(s + 2), aldk(s + 2), lA[(s + 2) % 3], t);
    }
    if (s == 6 || s == 8 || s == 10) {
#pragma unroll
      for (int mf = 0; mf < 4; ++mf)
#pragma unroll
        for (int g = 0; g < 4; ++g) acc2[mf][g] = zzero;
    }
    const u16* cA = lA[s % 3];
    const u16* cB = lB[s % 3];
#pragma unroll
    for (int h = 0; h < 2; ++h) {
      bf16x8 bfr[4];
#pragma unroll
      for (int g = 0; g < 4; ++g)
        bfr[g] = *(const bf16x8*)&cB[swz(g * 64 + wn * 16 + lr, h * 32 + kg * 8)];
#pragma unroll
      for (int mf = 0; mf < 4; ++mf) {
        bf16x8 afr = *(const bf16x8*)&cA[swz(wm * 64 + mf * 16 + lr, h * 32 + kg * 8)];
#pragma unroll
        for (int g = 0; g < 4; ++g) {
          if (s < 6)
            acc1[mf][g] = __builtin_amdgcn_mfma_f32_16x16x32_bf16(afr, bfr[g], acc1[mf][g], 0, 0, 0);
          else
            acc2[mf][g] = __builtin_amdgcn_mfma_f32_16x16x32_bf16(afr, bfr[g], acc2[mf][g], 0, 0, 0);
        }
      }
    }
    if (s == 7) {        // acc1 *= d_yh
#pragma unroll
      for (int mf = 0; mf < 4; ++mf)
#pragma unroll
        for (int g = 0; g < 4; ++g)
#pragma unroll
          for (int r = 0; r < 4; ++r) acc1[mf][g][r] *= (acc2[mf][g][r] + bh4[g]);
    } else if (s == 9) { // acc1 *= d_yx
#pragma unroll
      for (int mf = 0; mf < 4; ++mf)
#pragma unroll
        for (int g = 0; g < 4; ++g)
#pragma unroll
          for (int r = 0; r < 4; ++r) acc1[mf][g][r] *= (acc2[mf][g][r] + bx4[g]);
    }
    if (s < 10) wait6_bar();
    else if (s == 10) wait0_bar();
  }

  // ---- epilogue: main LSTM cell (acc2 holds d_yb)
  const int hcol = hb * 64 + wn * 16 + lr;
  float* out_c1 = d_out + (size_t)BATCH * 256;
#pragma unroll
  for (int mf = 0; mf < 4; ++mf)
#pragma unroll
    for (int r = 0; r < 4; ++r) {
      const int row = rb * 128 + wm * 64 + mf * 16 + kg * 4 + r;
      const float gi = acc1[mf][0][r] + acc2[mf][0][r] + b4[0];
      const float gg = acc1[mf][1][r] + acc2[mf][1][r] + b4[1];
      const float gf = acc1[mf][2][r] + acc2[mf][2][r] + b4[2];
      const float go = acc1[mf][3][r] + acc2[mf][3][r] + b4[3];
      const float c0v = c0[(size_t)row * 256 + hcol];
      const float c1v = sigf(gf) * c0v + sigf(gi) * tanhf(gg);
      const float h1v = sigf(go) * tanhf(c1v);
      d_out[(size_t)row * 256 + hcol]  = h1v;
      out_c1[(size_t)row * 256 + hcol] = c1v;
    }
}

// ---------------------------------------------------------------------------
extern "C" void kernel_launch(void* const* d_in, const int* in_sizes, int n_in,
                              void* d_out, int out_size, void* d_ws, size_t ws_size,
                              hipStream_t stream)
{
  (void)in_sizes; (void)n_in; (void)out_size; (void)ws_size;
  const float* x       = (const float*)d_in[0];
  const float* h0      = (const float*)d_in[1];
  const float* c0      = (const float*)d_in[2];
  const float* hhat0   = (const float*)d_in[3];
  const float* chat0   = (const float*)d_in[4];
  const float* hweight = (const float*)d_in[5];
  const float* hbias   = (const float*)d_in[6];
  const float* zw_h    = (const float*)d_in[7];
  const float* zw_x    = (const float*)d_in[8];
  const float* zw_b    = (const float*)d_in[9];
  const float* zb_h    = (const float*)d_in[10];
  const float* zb_x    = (const float*)d_in[11];
  const float* dw_h    = (const float*)d_in[12];
  const float* dw_x    = (const float*)d_in[13];
  const float* dw_b    = (const float*)d_in[14];
  const float* weight  = (const float*)d_in[15];
  const float* bias    = (const float*)d_in[16];

  // workspace layout (bytes, 16B-aligned); total ~86 MB
  char* wsb = (char*)d_ws;
  u16*   abuf    = (u16*)(wsb + 0);              // B*512*2   = 67108864
  u16*   hbuf    = (u16*)(wsb + 67108864);       // B*128*2   = 16777216
  u16*   hw_ts   = (u16*)(wsb + 83886080);       // 2*8*16384*2 = 524288
  u16*   w_ts    = (u16*)(wsb + 84410368);       // 4*6*16384*2 = 786432
  u16*   whp_ts  = (u16*)(wsb + 85196800);       // 4*2*16384*2 = 262144
  u16*   wxp_ts  = (u16*)(wsb + 85458944);
  u16*   wbp_ts  = (u16*)(wsb + 85721088);
  float* hbias_r = (float*)(wsb + 85983232);     // 512*4
  float* bias_r  = (float*)(wsb + 85985280);     // 1024*4
  float* bhp_r   = (float*)(wsb + 85989376);     // 1024*4
  float* bxp_r   = (float*)(wsb + 85993472);     // 1024*4

  hlstm_pre<<<dim3(4608), dim3(256), 0, stream>>>(
      hhat0, h0, x, abuf,
      hweight, hbias, zw_h, zw_x, zw_b, zb_h, zb_x, dw_h, dw_x, dw_b, weight, bias,
      hw_ts, hbias_r, w_ts, bias_r, whp_ts, wxp_ts, wbp_ts, bhp_r, bxp_r);

  hlstm_k1<<<dim3(1024), dim3(512), 0, stream>>>(
      abuf, chat0, hw_ts, hbias_r, (float*)d_out, hbuf);

  hlstm_k2<<<dim3(2048), dim3(512), 0, stream>>>(
      abuf, hbuf, c0, w_ts, bias_r, whp_ts, wxp_ts, wbp_ts, bhp_r, bxp_r, (float*)d_out);
}